// Round 5
// baseline (867.409 us; speedup 1.0000x reference)
//
#include <hip/hip_runtime.h>
#include <hip/hip_fp16.h>

constexpr int NN = 100000;   // nodes
constexpr int EE = 3200000;  // edges
constexpr int GG = 5000;     // graphs
constexpr float BNEPS = 1e-5f;

constexpr int XCDS = 8;
constexpr int NODES_PER_XCD = (NN + XCDS - 1) / XCDS;  // 12500

constexpr int SCAN_BLK = 256;
constexpr int SCAN_ITEMS = 1024;                       // 256 thr x 4
constexpr int NSCANBLK = (NN + SCAN_ITEMS - 1) / SCAN_ITEMS;  // 98

// ---------------- CSR build (XCD-partitioned by dst range) ----------------

__global__ void count_x(const int* __restrict__ ei, int* __restrict__ cnt) {
    const int r = blockIdx.x & 7;
    const int bi = blockIdx.x >> 3;
    const int grpThreads = (gridDim.x >> 3) * blockDim.x;
    const int lo = r * NODES_PER_XCD;
    const int hi = (lo + NODES_PER_XCD < NN) ? lo + NODES_PER_XCD : NN;
    const int4* d4 = (const int4*)(ei + EE);
    for (int q = bi * blockDim.x + threadIdx.x; q < EE / 4; q += grpThreads) {
        int4 d = d4[q];
        if (d.x >= lo && d.x < hi) atomicAdd(&cnt[d.x], 1);
        if (d.y >= lo && d.y < hi) atomicAdd(&cnt[d.y], 1);
        if (d.z >= lo && d.z < hi) atomicAdd(&cnt[d.z], 1);
        if (d.w >= lo && d.w < hi) atomicAdd(&cnt[d.w], 1);
    }
}

__global__ void scatter_x(const int* __restrict__ ei, int* __restrict__ fill,
                          int* __restrict__ colA) {
    const int r = blockIdx.x & 7;
    const int bi = blockIdx.x >> 3;
    const int grpThreads = (gridDim.x >> 3) * blockDim.x;
    const int lo = r * NODES_PER_XCD;
    const int hi = (lo + NODES_PER_XCD < NN) ? lo + NODES_PER_XCD : NN;
    const int4* d4 = (const int4*)(ei + EE);
    const int4* s4 = (const int4*)ei;
    for (int q = bi * blockDim.x + threadIdx.x; q < EE / 4; q += grpThreads) {
        int4 d = d4[q];
        int4 s = s4[q];
        if (d.x >= lo && d.x < hi) colA[atomicAdd(&fill[d.x], 1)] = s.x;
        if (d.y >= lo && d.y < hi) colA[atomicAdd(&fill[d.y], 1)] = s.y;
        if (d.z >= lo && d.z < hi) colA[atomicAdd(&fill[d.z], 1)] = s.z;
        if (d.w >= lo && d.w < hi) colA[atomicAdd(&fill[d.w], 1)] = s.w;
    }
}

// ---------------- prefix scan over cnt -> rowptr, dinv, fill cursors ----------------

__global__ void scanA(const int* __restrict__ cnt, int* __restrict__ bsum) {
    __shared__ int ls[SCAN_BLK];
    int t = threadIdx.x;
    int base = blockIdx.x * SCAN_ITEMS + t * 4;
    int s = 0;
#pragma unroll
    for (int k = 0; k < 4; ++k) { int i = base + k; if (i < NN) s += cnt[i]; }
    ls[t] = s; __syncthreads();
    for (int off = 128; off > 0; off >>= 1) {
        if (t < off) ls[t] += ls[t + off];
        __syncthreads();
    }
    if (t == 0) bsum[blockIdx.x] = ls[0];
}

__global__ void scanB(const int* __restrict__ bsum, int* __restrict__ boff) {
    __shared__ int ls[SCAN_BLK];
    int t = threadIdx.x;
    int v = (t < NSCANBLK) ? bsum[t] : 0;
    ls[t] = v; __syncthreads();
    for (int off = 1; off < SCAN_BLK; off <<= 1) {
        int x = 0;
        if (t >= off) x = ls[t - off];
        __syncthreads();
        ls[t] += x;
        __syncthreads();
    }
    if (t < NSCANBLK) boff[t] = ls[t] - v;  // exclusive
}

__global__ void scanC(int* __restrict__ cnt /* becomes fill-start */, const int* __restrict__ boff,
                      int* __restrict__ rowptr, float* __restrict__ dinv) {
    __shared__ int ls[SCAN_BLK];
    int t = threadIdx.x;
    int base = blockIdx.x * SCAN_ITEMS + t * 4;
    int c[4]; int s = 0;
#pragma unroll
    for (int k = 0; k < 4; ++k) { int i = base + k; c[k] = (i < NN) ? cnt[i] : 0; s += c[k]; }
    ls[t] = s; __syncthreads();
    for (int off = 1; off < SCAN_BLK; off <<= 1) {
        int x = 0;
        if (t >= off) x = ls[t - off];
        __syncthreads();
        ls[t] += x;
        __syncthreads();
    }
    int run = boff[blockIdx.x] + ls[t] - s;  // exclusive base for this thread
#pragma unroll
    for (int k = 0; k < 4; ++k) {
        int i = base + k;
        if (i < NN) {
            rowptr[i] = run;
            cnt[i] = run;  // fill cursor for scatter
            dinv[i] = rsqrtf((float)(c[k] + 1));  // +1 self-loop
            run += c[k];
            if (i == NN - 1) rowptr[NN] = run;
        }
    }
}

// ---------------- x pre-scale: xsc[n][k] = half(x[n][k] * dinv[n]), 20 ch tight ----------------

__global__ void scale_x(const float* __restrict__ x, const float* __restrict__ dinv,
                        __half* __restrict__ xsc) {
    int idx = blockIdx.x * blockDim.x + threadIdx.x;
    if (idx < NN * 20) {
        int n = idx / 20;
        xsc[idx] = __float2half(x[idx] * dinv[n]);
    }
}

// ---------------- GEMM: optional BN-affine+ReLU on input; two epilogues ----------------

template <int FIN, int FOUT, bool AFFINE, bool SCALED>
__global__ void gemm_k(const float* __restrict__ hin, const float* __restrict__ aArr,
                       const float* __restrict__ bArr, const float* __restrict__ W,
                       const float* __restrict__ dinv, const float* __restrict__ bias,
                       float* __restrict__ outF, __half* __restrict__ outH) {
    constexpr int NB = 256 / FOUT;  // nodes per group
    __shared__ float Wl[FIN * FOUT];
    __shared__ float rows[NB][FIN];
    const int t = threadIdx.x;
    for (int i = t; i < FIN * FOUT; i += 256) Wl[i] = W[i];
    const int c = t % FOUT, s = t / FOUT;
    const int ngrp = (NN + NB - 1) / NB;
    for (int grp = blockIdx.x; grp < ngrp; grp += gridDim.x) {
        __syncthreads();
        for (int i = t; i < NB * FIN; i += 256) {
            int sn = i / FIN, k = i % FIN;
            int n2 = grp * NB + sn;
            float v = 0.f;
            if (n2 < NN) {
                v = hin[(size_t)n2 * FIN + k];
                if constexpr (AFFINE) {
                    v = aArr[k] * v + bArr[k];
                    v = v > 0.f ? v : 0.f;
                }
            }
            rows[sn][k] = v;
        }
        __syncthreads();
        int node = grp * NB + s;
        if (node < NN) {
            float acc = 0.f;
#pragma unroll
            for (int k = 0; k < FIN; ++k) acc += rows[s][k] * Wl[k * FOUT + c];
            if constexpr (SCALED)
                outH[(size_t)node * FOUT + c] = __float2half(acc * dinv[node]);
            else
                outF[(size_t)node * FOUT + c] = acc + bias[c];
        }
    }
}

// ---------------- gather aggregation, half2-per-lane (layer 1, 40 B rows) ----------------

template <int H2, int OUTF>
__global__ void agg_half(const __half2* __restrict__ src, const int* __restrict__ rowptr,
                         const int* __restrict__ colA, const float* __restrict__ dinv,
                         const float* __restrict__ bias, float* __restrict__ out) {
    constexpr int SUB = 64 / H2;
    const int lane = threadIdx.x & 63;
    const int wid = (blockIdx.x * blockDim.x + threadIdx.x) >> 6;
    const int totalWaves = (gridDim.x * blockDim.x) >> 6;
    const int f = lane % H2;
    const int sub = lane / H2;
    const int stride = totalWaves * SUB;
    float bx = 0.f, by = 0.f;
    if (bias != nullptr) {
        bx = bias[2 * f];
        by = (2 * f + 1 < OUTF) ? bias[2 * f + 1] : 0.f;
    }
    const int i0 = (sub < SUB) ? wid * SUB + sub : NN;  // idle tail lanes skip
    for (int i = i0; i < NN; i += stride) {
        const int r0 = rowptr[i], r1 = rowptr[i + 1];
        float2 acc = __half22float2(src[(size_t)i * H2 + f]);
        float2 acc2 = {0.f, 0.f};
        int e = r0;
        for (; e + 3 < r1; e += 4) {
            int j0 = colA[e], j1 = colA[e + 1], j2 = colA[e + 2], j3 = colA[e + 3];
            float2 v0 = __half22float2(src[(size_t)j0 * H2 + f]);
            float2 v1 = __half22float2(src[(size_t)j1 * H2 + f]);
            float2 v2 = __half22float2(src[(size_t)j2 * H2 + f]);
            float2 v3 = __half22float2(src[(size_t)j3 * H2 + f]);
            acc.x += v0.x + v1.x;
            acc.y += v0.y + v1.y;
            acc2.x += v2.x + v3.x;
            acc2.y += v2.y + v3.y;
        }
        for (; e < r1; ++e) {
            float2 v = __half22float2(src[(size_t)colA[e] * H2 + f]);
            acc.x += v.x; acc.y += v.y;
        }
        acc.x += acc2.x; acc.y += acc2.y;
        const float d = dinv[i];
        out[(size_t)i * OUTF + 2 * f] = d * acc.x + bx;
        if (2 * f + 1 < OUTF) out[(size_t)i * OUTF + 2 * f + 1] = d * acc.y + by;
    }
}

// ---------------- gather aggregation, float4-per-lane (layers 2/3) ----------------
// fp16 rows of F4 float4s (16 B each); lane owns one float4 slot (8 channels).
// SUB = 64/F4 nodes per wave. out[i][c] = dinv[i]*sum + bias[c], OUTF = 8*F4.

template <int F4, int OUTF>
__global__ void agg_f4(const float4* __restrict__ src, const int* __restrict__ rowptr,
                       const int* __restrict__ colA, const float* __restrict__ dinv,
                       const float* __restrict__ bias, float* __restrict__ out) {
    constexpr int SUB = 64 / F4;
    const int lane = threadIdx.x & 63;
    const int wid = (blockIdx.x * blockDim.x + threadIdx.x) >> 6;
    const int totalWaves = (gridDim.x * blockDim.x) >> 6;
    const int c4 = lane % F4;
    const int sub = lane / F4;
    const int stride = totalWaves * SUB;
    float bx[8];
#pragma unroll
    for (int k = 0; k < 8; ++k) bx[k] = (bias != nullptr) ? bias[c4 * 8 + k] : 0.f;
    for (int i = wid * SUB + sub; i < NN; i += stride) {
        const int r0 = rowptr[i], r1 = rowptr[i + 1];
        float acc[8];
        {
            float4 sv = src[(size_t)i * F4 + c4];  // self loop (pre-scaled by dinv[i])
            const __half2* hx = (const __half2*)&sv;
#pragma unroll
            for (int k = 0; k < 4; ++k) {
                float2 f = __half22float2(hx[k]);
                acc[2 * k] = f.x; acc[2 * k + 1] = f.y;
            }
        }
        int e = r0;
        for (; e + 1 < r1; e += 2) {
            int j0 = colA[e], j1 = colA[e + 1];
            float4 v0 = src[(size_t)j0 * F4 + c4];
            float4 v1 = src[(size_t)j1 * F4 + c4];
            const __half2* h0 = (const __half2*)&v0;
            const __half2* h1 = (const __half2*)&v1;
#pragma unroll
            for (int k = 0; k < 4; ++k) {
                float2 f0 = __half22float2(h0[k]);
                float2 f1 = __half22float2(h1[k]);
                acc[2 * k] += f0.x + f1.x;
                acc[2 * k + 1] += f0.y + f1.y;
            }
        }
        if (e < r1) {
            float4 v0 = src[(size_t)colA[e] * F4 + c4];
            const __half2* h0 = (const __half2*)&v0;
#pragma unroll
            for (int k = 0; k < 4; ++k) {
                float2 f0 = __half22float2(h0[k]);
                acc[2 * k] += f0.x;
                acc[2 * k + 1] += f0.y;
            }
        }
        const float d = dinv[i];
#pragma unroll
        for (int k = 0; k < 8; ++k) out[(size_t)i * OUTF + c4 * 8 + k] = d * acc[k] + bx[k];
    }
}

// ---------------- BN stats ----------------

template <int F>
__global__ void bn_stats(const float* __restrict__ h, float* __restrict__ sums,
                         float* __restrict__ ssq) {
    __shared__ float ls[F], lq[F];
    const int t = threadIdx.x;
    const int c = t % F;
    constexpr int ROWS = 256 / F;
    float s = 0.f, q = 0.f;
    for (int n = blockIdx.x * ROWS + t / F; n < NN; n += gridDim.x * ROWS) {
        float v = h[(size_t)n * F + c];
        s += v; q += v * v;
    }
    if (t < F) { ls[t] = 0.f; lq[t] = 0.f; }
    __syncthreads();
    atomicAdd(&ls[c], s);
    atomicAdd(&lq[c], q);
    __syncthreads();
    if (t < F) { atomicAdd(&sums[t], ls[t]); atomicAdd(&ssq[t], lq[t]); }
}

template <int F>
__global__ void bn_finalize(const float* __restrict__ sums, const float* __restrict__ ssq,
                            const float* __restrict__ g, const float* __restrict__ be,
                            float* __restrict__ aArr, float* __restrict__ bArr) {
    int c = threadIdx.x;
    if (c < F) {
        float mu = sums[c] / (float)NN;
        float var = ssq[c] / (float)NN - mu * mu;
        float a = g[c] * rsqrtf(var + BNEPS);
        aArr[c] = a;
        bArr[c] = be[c] - mu * a;
    }
}

// ---------------- GAT: xg = relu(bn(h3)) @ Wg (fp16) ; a_src/a_dst (fp32) ----------------

__global__ void gat_pre(const float* __restrict__ out3, const float* __restrict__ aArr,
                        const float* __restrict__ bArr, const float* __restrict__ Wg,
                        const float* __restrict__ att_src, const float* __restrict__ att_dst,
                        __half* __restrict__ xg, float* __restrict__ asrc,
                        float* __restrict__ adst) {
    __shared__ float Wl[16 * 128];
    __shared__ float row[2][16];
    __shared__ float red[2][128];
    const int t = threadIdx.x;
    for (int i = t; i < 16 * 128; i += 256) Wl[i] = Wg[i];
    const int c = t & 127, s = t >> 7;
    const float atts = att_src[c], attd = att_dst[c];
    const int h = c >> 4;
    const int cc = c & 15;
    const int ngrp = (NN + 1) / 2;
    for (int grp = blockIdx.x; grp < ngrp; grp += gridDim.x) {
        __syncthreads();
        if (t < 32) {
            int sn = t >> 4, k = t & 15;
            int n2 = grp * 2 + sn;
            float v = 0.f;
            if (n2 < NN) {
                v = out3[n2 * 16 + k];
                v = aArr[k] * v + bArr[k];
                v = v > 0.f ? v : 0.f;
            }
            row[sn][k] = v;
        }
        __syncthreads();
        float acc = 0.f;
#pragma unroll
        for (int k = 0; k < 16; ++k) acc += row[s][k] * Wl[k * 128 + c];
        int node = grp * 2 + s;
        if (node < NN) xg[(size_t)node * 128 + c] = __float2half(acc);
        red[s][c] = acc * atts;
        __syncthreads();
        if (cc == 0 && node < NN) {
            float v = 0.f;
#pragma unroll
            for (int k2 = 0; k2 < 16; ++k2) v += red[s][h * 16 + k2];
            asrc[node * 8 + h] = v;
        }
        __syncthreads();
        red[s][c] = acc * attd;
        __syncthreads();
        if (cc == 0 && node < NN) {
            float v = 0.f;
#pragma unroll
            for (int k2 = 0; k2 < 16; ++k2) v += red[s][h * 16 + k2];
            adst[node * 8 + h] = v;
        }
    }
}

// ---------------- GAT single-pass, float4 gathers: 16 lanes x 16 B per row, 4 edges/iter ----------------
// lane = 16*sub + c16. Lane covers channels [8*c16, 8*c16+8) -> single head (c16>>1).

__device__ __forceinline__ float leaky02(float x) { return x > 0.f ? x : 0.2f * x; }

__global__ void gat_agg4(const float4* __restrict__ xg4, const float* __restrict__ asrc,
                         const float* __restrict__ adst, const int* __restrict__ rowptr,
                         const int* __restrict__ colA, const float* __restrict__ bg,
                         float* __restrict__ hg) {
    const int lane = threadIdx.x & 63;
    const int c16 = lane & 15;
    const int sub = lane >> 4;
    const int head = c16 >> 1;
    const int wid = (blockIdx.x * blockDim.x + threadIdx.x) >> 6;
    const int totalWaves = (gridDim.x * blockDim.x) >> 6;
    for (int i = wid; i < NN; i += totalWaves) {
        const int r0 = rowptr[i], r1 = rowptr[i + 1];
        const float adh = adst[i * 8 + head];
        float acc[8];
        float wsum;
        {   // self loop: only sub 0 contributes (summed once in sub-reduction)
            float w = (sub == 0) ? __expf(leaky02(asrc[i * 8 + head] + adh)) : 0.f;
            float4 xv = xg4[(size_t)i * 16 + c16];
            const __half2* hx = (const __half2*)&xv;
#pragma unroll
            for (int k = 0; k < 4; ++k) {
                float2 f = __half22float2(hx[k]);
                acc[2 * k] = w * f.x;
                acc[2 * k + 1] = w * f.y;
            }
            wsum = w;
        }
        for (int e = r0; e < r1; e += 4) {
            const int ee = e + sub;
            const bool val = ee < r1;
            int j = i;
            if (val) j = colA[ee];
            float w = val ? __expf(leaky02(asrc[j * 8 + head] + adh)) : 0.f;
            float4 xv = xg4[(size_t)j * 16 + c16];
            const __half2* hx = (const __half2*)&xv;
#pragma unroll
            for (int k = 0; k < 4; ++k) {
                float2 f = __half22float2(hx[k]);
                acc[2 * k] += w * f.x;
                acc[2 * k + 1] += w * f.y;
            }
            wsum += w;
        }
        // reduce over subs (lanes ^16, ^32); wsum becomes per-head total
#pragma unroll
        for (int off = 16; off < 64; off <<= 1) {
#pragma unroll
            for (int k = 0; k < 8; ++k) acc[k] += __shfl_xor(acc[k], off);
            wsum += __shfl_xor(wsum, off);
        }
        const float s = 0.125f / wsum;  // normalize + head-mean factor
#pragma unroll
        for (int k = 0; k < 8; ++k) acc[k] *= s;
        // head mean: sum lanes over c16 bits 1..3 (same parity class = same output channels)
#pragma unroll
        for (int off = 2; off < 16; off <<= 1) {
#pragma unroll
            for (int k = 0; k < 8; ++k) acc[k] += __shfl_xor(acc[k], off);
        }
        if (lane < 2) {
            const int base = i * 16 + lane * 8;
#pragma unroll
            for (int k = 0; k < 8; ++k) hg[base + k] = acc[k] + bg[lane * 8 + k];
        }
    }
}

// ---------------- pool + final ----------------

__global__ void pool_kernel(const float* __restrict__ hg, const int* __restrict__ batch,
                            float* __restrict__ pooled) {
    int idx = blockIdx.x * blockDim.x + threadIdx.x;
    if (idx < NN * 16) {
        int n = idx >> 4, c = idx & 15;
        atomicAdd(&pooled[batch[n] * 16 + c], hg[idx]);
    }
}

__global__ void final_kernel(const float* __restrict__ pooled, const float* __restrict__ Wf,
                             const float* __restrict__ bf, float* __restrict__ out) {
    int idx = blockIdx.x * blockDim.x + threadIdx.x;
    if (idx < GG * 3) {
        int g = idx / 3, j = idx - g * 3;
        float acc = bf[j];
#pragma unroll
        for (int c = 0; c < 16; ++c) acc += pooled[g * 16 + c] * Wf[c * 3 + j];
        out[idx] = acc;
    }
}

// ---------------- launcher ----------------

extern "C" void kernel_launch(void* const* d_in, const int* in_sizes, int n_in,
                              void* d_out, int out_size, void* d_ws, size_t ws_size,
                              hipStream_t stream) {
    const float* x = (const float*)d_in[0];
    const int* ei = (const int*)d_in[1];
    const int* batch = (const int*)d_in[2];
    const float* W1 = (const float*)d_in[3];  const float* b1 = (const float*)d_in[4];
    const float* g1 = (const float*)d_in[5];  const float* be1 = (const float*)d_in[6];
    const float* W2 = (const float*)d_in[7];  const float* b2 = (const float*)d_in[8];
    const float* g2 = (const float*)d_in[9];  const float* be2 = (const float*)d_in[10];
    const float* W3 = (const float*)d_in[11]; const float* b3 = (const float*)d_in[12];
    const float* g3 = (const float*)d_in[13]; const float* be3 = (const float*)d_in[14];
    const float* Wg = (const float*)d_in[15];
    const float* att_src = (const float*)d_in[16];
    const float* att_dst = (const float*)d_in[17];
    const float* bg = (const float*)d_in[18];
    const float* Wf = (const float*)d_in[19];
    const float* bf = (const float*)d_in[20];
    float* out = (float*)d_out;

    char* w = (char*)d_ws;
    auto alloc = [&](size_t bytes) -> char* {
        char* p = w;
        w += (bytes + 255) & ~(size_t)255;
        return p;
    };
    // --- zeroed region (one memset) ---
    int* fill = (int*)alloc((size_t)NN * 4);
    float* pooled = (float*)alloc((size_t)GG * 16 * 4);
    float* sums1 = (float*)alloc(64 * 4); float* ssq1 = (float*)alloc(64 * 4);
    float* sums2 = (float*)alloc(32 * 4); float* ssq2 = (float*)alloc(32 * 4);
    float* sums3 = (float*)alloc(16 * 4); float* ssq3 = (float*)alloc(16 * 4);
    size_t zeroBytes = (size_t)(w - (char*)d_ws);
    // --- rest ---
    float* a1 = (float*)alloc(64 * 4); float* bh1 = (float*)alloc(64 * 4);
    float* a2 = (float*)alloc(32 * 4); float* bh2 = (float*)alloc(32 * 4);
    float* a3 = (float*)alloc(16 * 4); float* bh3 = (float*)alloc(16 * 4);
    int* bsum = (int*)alloc(128 * 4);
    int* boff = (int*)alloc(128 * 4);
    int* rowptr = (int*)alloc((size_t)(NN + 1) * 4);
    int* colA = (int*)alloc((size_t)EE * 4);
    float* dinv = (float*)alloc((size_t)NN * 4);
    char* A = alloc((size_t)NN * 64 * 4);  // 25.6 MB scratch block A
    char* B = alloc((size_t)NN * 64 * 4);  // 25.6 MB scratch block B

    // lifetime-based aliases
    __half* xsc  = (__half*)B;                               // [NN,20] fp16   4.0 MB
    float*  aggx = (float*)(B + (size_t)NN * 32 * 2);        // [NN,20] fp32   8.0 MB
    float*  h1   = (float*)A;                                // [NN,64] fp32  25.6 MB
    __half* hs2  = (__half*)B;                               // [NN,32] fp16   6.4 MB
    float*  h2   = (float*)(B + (size_t)NN * 32 * 2);        // [NN,32] fp32  12.8 MB
    __half* hs3  = (__half*)A;                               // [NN,16] fp16   3.2 MB
    float*  h3   = (float*)(A + (size_t)NN * 16 * 2);        // [NN,16] fp32   6.4 MB
    __half* xgh  = (__half*)B;                               // [NN,128] fp16 25.6 MB
    float*  asrc = (float*)(A + (size_t)NN * 24 * 4);        // [NN,8]  fp32   3.2 MB
    float*  adst = (float*)(A + (size_t)NN * 32 * 4);        // [NN,8]  fp32   3.2 MB
    float*  hg   = (float*)(A + (size_t)NN * 40 * 4);        // [NN,16] fp32   6.4 MB

    hipMemsetAsync(d_ws, 0, zeroBytes, stream);

    count_x<<<2048, 256, 0, stream>>>(ei, fill);
    scanA<<<NSCANBLK, SCAN_BLK, 0, stream>>>(fill, bsum);
    scanB<<<1, SCAN_BLK, 0, stream>>>(bsum, boff);
    scanC<<<NSCANBLK, SCAN_BLK, 0, stream>>>(fill, boff, rowptr, dinv);
    scatter_x<<<2048, 256, 0, stream>>>(ei, fill, colA);

    // layer 1: aggregate x first (20ch tight fp16), then GEMM 20->64 (+b1)
    scale_x<<<(NN * 20 + 255) / 256, 256, 0, stream>>>(x, dinv, xsc);
    agg_half<10, 20><<<2048, 256, 0, stream>>>((const __half2*)xsc, rowptr, colA, dinv, nullptr, aggx);
    gemm_k<20, 64, false, false><<<2048, 256, 0, stream>>>(aggx, nullptr, nullptr, W1, dinv, b1, h1, nullptr);
    bn_stats<64><<<512, 256, 0, stream>>>(h1, sums1, ssq1);
    bn_finalize<64><<<1, 64, 0, stream>>>(sums1, ssq1, g1, be1, a1, bh1);

    // layer 2: 64 -> 32 (fp16 pre-agg buffer, float4 gathers)
    gemm_k<64, 32, true, true><<<2048, 256, 0, stream>>>(h1, a1, bh1, W2, dinv, nullptr, nullptr, hs2);
    agg_f4<4, 32><<<2048, 256, 0, stream>>>((const float4*)hs2, rowptr, colA, dinv, b2, h2);
    bn_stats<32><<<512, 256, 0, stream>>>(h2, sums2, ssq2);
    bn_finalize<32><<<1, 64, 0, stream>>>(sums2, ssq2, g2, be2, a2, bh2);

    // layer 3: 32 -> 16 (fp16 pre-agg buffer, float4 gathers)
    gemm_k<32, 16, true, true><<<2048, 256, 0, stream>>>(h2, a2, bh2, W3, dinv, nullptr, nullptr, hs3);
    agg_f4<2, 16><<<2048, 256, 0, stream>>>((const float4*)hs3, rowptr, colA, dinv, b3, h3);
    bn_stats<16><<<512, 256, 0, stream>>>(h3, sums3, ssq3);
    bn_finalize<16><<<1, 64, 0, stream>>>(sums3, ssq3, g3, be3, a3, bh3);

    // GAT (fp16 xg), single-pass softmax+aggregate, float4 gathers
    gat_pre<<<2048, 256, 0, stream>>>(h3, a3, bh3, Wg, att_src, att_dst, xgh, asrc, adst);
    gat_agg4<<<2048, 256, 0, stream>>>((const float4*)xgh, asrc, adst, rowptr, colA, bg, hg);

    // pool + classify
    pool_kernel<<<(NN * 16 + 255) / 256, 256, 0, stream>>>(hg, batch, pooled);
    final_kernel<<<(GG * 3 + 255) / 256, 256, 0, stream>>>(pooled, Wf, bf, out);
}

// Round 6
// 729.479 us; speedup vs baseline: 1.1891x; 1.1891x over previous
//
#include <hip/hip_runtime.h>
#include <hip/hip_fp16.h>

constexpr int NN = 100000;   // nodes
constexpr int EE = 3200000;  // edges
constexpr int GG = 5000;     // graphs
constexpr float BNEPS = 1e-5f;

constexpr int XCDS = 8;
constexpr int NODES_PER_XCD = (NN + XCDS - 1) / XCDS;  // 12500

constexpr int SCAN_BLK = 256;
constexpr int SCAN_ITEMS = 1024;                       // 256 thr x 4
constexpr int NSCANBLK = (NN + SCAN_ITEMS - 1) / SCAN_ITEMS;  // 98

// ---------------- CSR build (XCD-partitioned by dst range) ----------------

__global__ void count_x(const int* __restrict__ ei, int* __restrict__ cnt) {
    const int r = blockIdx.x & 7;
    const int bi = blockIdx.x >> 3;
    const int grpThreads = (gridDim.x >> 3) * blockDim.x;
    const int lo = r * NODES_PER_XCD;
    const int hi = (lo + NODES_PER_XCD < NN) ? lo + NODES_PER_XCD : NN;
    const int4* d4 = (const int4*)(ei + EE);
    for (int q = bi * blockDim.x + threadIdx.x; q < EE / 4; q += grpThreads) {
        int4 d = d4[q];
        if (d.x >= lo && d.x < hi) atomicAdd(&cnt[d.x], 1);
        if (d.y >= lo && d.y < hi) atomicAdd(&cnt[d.y], 1);
        if (d.z >= lo && d.z < hi) atomicAdd(&cnt[d.z], 1);
        if (d.w >= lo && d.w < hi) atomicAdd(&cnt[d.w], 1);
    }
}

__global__ void scatter_x(const int* __restrict__ ei, int* __restrict__ fill,
                          int* __restrict__ colA) {
    const int r = blockIdx.x & 7;
    const int bi = blockIdx.x >> 3;
    const int grpThreads = (gridDim.x >> 3) * blockDim.x;
    const int lo = r * NODES_PER_XCD;
    const int hi = (lo + NODES_PER_XCD < NN) ? lo + NODES_PER_XCD : NN;
    const int4* d4 = (const int4*)(ei + EE);
    const int4* s4 = (const int4*)ei;
    for (int q = bi * blockDim.x + threadIdx.x; q < EE / 4; q += grpThreads) {
        int4 d = d4[q];
        int4 s = s4[q];
        if (d.x >= lo && d.x < hi) colA[atomicAdd(&fill[d.x], 1)] = s.x;
        if (d.y >= lo && d.y < hi) colA[atomicAdd(&fill[d.y], 1)] = s.y;
        if (d.z >= lo && d.z < hi) colA[atomicAdd(&fill[d.z], 1)] = s.z;
        if (d.w >= lo && d.w < hi) colA[atomicAdd(&fill[d.w], 1)] = s.w;
    }
}

// ---------------- prefix scan over cnt -> rowptr, dinv, fill cursors ----------------

__global__ void scanA(const int* __restrict__ cnt, int* __restrict__ bsum) {
    __shared__ int ls[SCAN_BLK];
    int t = threadIdx.x;
    int base = blockIdx.x * SCAN_ITEMS + t * 4;
    int s = 0;
#pragma unroll
    for (int k = 0; k < 4; ++k) { int i = base + k; if (i < NN) s += cnt[i]; }
    ls[t] = s; __syncthreads();
    for (int off = 128; off > 0; off >>= 1) {
        if (t < off) ls[t] += ls[t + off];
        __syncthreads();
    }
    if (t == 0) bsum[blockIdx.x] = ls[0];
}

__global__ void scanB(const int* __restrict__ bsum, int* __restrict__ boff) {
    __shared__ int ls[SCAN_BLK];
    int t = threadIdx.x;
    int v = (t < NSCANBLK) ? bsum[t] : 0;
    ls[t] = v; __syncthreads();
    for (int off = 1; off < SCAN_BLK; off <<= 1) {
        int x = 0;
        if (t >= off) x = ls[t - off];
        __syncthreads();
        ls[t] += x;
        __syncthreads();
    }
    if (t < NSCANBLK) boff[t] = ls[t] - v;  // exclusive
}

__global__ void scanC(int* __restrict__ cnt /* becomes fill-start */, const int* __restrict__ boff,
                      int* __restrict__ rowptr, float* __restrict__ dinv) {
    __shared__ int ls[SCAN_BLK];
    int t = threadIdx.x;
    int base = blockIdx.x * SCAN_ITEMS + t * 4;
    int c[4]; int s = 0;
#pragma unroll
    for (int k = 0; k < 4; ++k) { int i = base + k; c[k] = (i < NN) ? cnt[i] : 0; s += c[k]; }
    ls[t] = s; __syncthreads();
    for (int off = 1; off < SCAN_BLK; off <<= 1) {
        int x = 0;
        if (t >= off) x = ls[t - off];
        __syncthreads();
        ls[t] += x;
        __syncthreads();
    }
    int run = boff[blockIdx.x] + ls[t] - s;  // exclusive base for this thread
#pragma unroll
    for (int k = 0; k < 4; ++k) {
        int i = base + k;
        if (i < NN) {
            rowptr[i] = run;
            cnt[i] = run;  // fill cursor for scatter
            dinv[i] = rsqrtf((float)(c[k] + 1));  // +1 self-loop
            run += c[k];
            if (i == NN - 1) rowptr[NN] = run;
        }
    }
}

// ---------------- x pre-scale: xsc[n][k] = half(x[n][k] * dinv[n]), 20 ch tight ----------------

__global__ void scale_x(const float* __restrict__ x, const float* __restrict__ dinv,
                        __half* __restrict__ xsc) {
    int idx = blockIdx.x * blockDim.x + threadIdx.x;
    if (idx < NN * 20) {
        int n = idx / 20;
        xsc[idx] = __float2half(x[idx] * dinv[n]);
    }
}

// ---------------- GEMM: optional BN-affine+ReLU on input; two epilogues ----------------

template <int FIN, int FOUT, bool AFFINE, bool SCALED>
__global__ void gemm_k(const float* __restrict__ hin, const float* __restrict__ aArr,
                       const float* __restrict__ bArr, const float* __restrict__ W,
                       const float* __restrict__ dinv, const float* __restrict__ bias,
                       float* __restrict__ outF, __half* __restrict__ outH) {
    constexpr int NB = 256 / FOUT;  // nodes per group
    __shared__ float Wl[FIN * FOUT];
    __shared__ float rows[NB][FIN];
    const int t = threadIdx.x;
    for (int i = t; i < FIN * FOUT; i += 256) Wl[i] = W[i];
    const int c = t % FOUT, s = t / FOUT;
    const int ngrp = (NN + NB - 1) / NB;
    for (int grp = blockIdx.x; grp < ngrp; grp += gridDim.x) {
        __syncthreads();
        for (int i = t; i < NB * FIN; i += 256) {
            int sn = i / FIN, k = i % FIN;
            int n2 = grp * NB + sn;
            float v = 0.f;
            if (n2 < NN) {
                v = hin[(size_t)n2 * FIN + k];
                if constexpr (AFFINE) {
                    v = aArr[k] * v + bArr[k];
                    v = v > 0.f ? v : 0.f;
                }
            }
            rows[sn][k] = v;
        }
        __syncthreads();
        int node = grp * NB + s;
        if (node < NN) {
            float acc = 0.f;
#pragma unroll
            for (int k = 0; k < FIN; ++k) acc += rows[s][k] * Wl[k * FOUT + c];
            if constexpr (SCALED)
                outH[(size_t)node * FOUT + c] = __float2half(acc * dinv[node]);
            else
                outF[(size_t)node * FOUT + c] = acc + bias[c];
        }
    }
}

// ---------------- gather aggregation, half2-per-lane ----------------

template <int H2, int OUTF>
__global__ void agg_half(const __half2* __restrict__ src, const int* __restrict__ rowptr,
                         const int* __restrict__ colA, const float* __restrict__ dinv,
                         const float* __restrict__ bias, float* __restrict__ out) {
    constexpr int SUB = 64 / H2;
    const int lane = threadIdx.x & 63;
    const int wid = (blockIdx.x * blockDim.x + threadIdx.x) >> 6;
    const int totalWaves = (gridDim.x * blockDim.x) >> 6;
    const int f = lane % H2;
    const int sub = lane / H2;
    const int stride = totalWaves * SUB;
    float bx = 0.f, by = 0.f;
    if (bias != nullptr) {
        bx = bias[2 * f];
        by = (2 * f + 1 < OUTF) ? bias[2 * f + 1] : 0.f;
    }
    const int i0 = (sub < SUB) ? wid * SUB + sub : NN;  // idle tail lanes skip
    for (int i = i0; i < NN; i += stride) {
        const int r0 = rowptr[i], r1 = rowptr[i + 1];
        float2 acc = __half22float2(src[(size_t)i * H2 + f]);
        float2 acc2 = {0.f, 0.f};
        int e = r0;
        for (; e + 3 < r1; e += 4) {
            int j0 = colA[e], j1 = colA[e + 1], j2 = colA[e + 2], j3 = colA[e + 3];
            float2 v0 = __half22float2(src[(size_t)j0 * H2 + f]);
            float2 v1 = __half22float2(src[(size_t)j1 * H2 + f]);
            float2 v2 = __half22float2(src[(size_t)j2 * H2 + f]);
            float2 v3 = __half22float2(src[(size_t)j3 * H2 + f]);
            acc.x += v0.x + v1.x;
            acc.y += v0.y + v1.y;
            acc2.x += v2.x + v3.x;
            acc2.y += v2.y + v3.y;
        }
        for (; e < r1; ++e) {
            float2 v = __half22float2(src[(size_t)colA[e] * H2 + f]);
            acc.x += v.x; acc.y += v.y;
        }
        acc.x += acc2.x; acc.y += acc2.y;
        const float d = dinv[i];
        out[(size_t)i * OUTF + 2 * f] = d * acc.x + bx;
        if (2 * f + 1 < OUTF) out[(size_t)i * OUTF + 2 * f + 1] = d * acc.y + by;
    }
}

// ---------------- BN stats ----------------

template <int F>
__global__ void bn_stats(const float* __restrict__ h, float* __restrict__ sums,
                         float* __restrict__ ssq) {
    __shared__ float ls[F], lq[F];
    const int t = threadIdx.x;
    const int c = t % F;
    constexpr int ROWS = 256 / F;
    float s = 0.f, q = 0.f;
    for (int n = blockIdx.x * ROWS + t / F; n < NN; n += gridDim.x * ROWS) {
        float v = h[(size_t)n * F + c];
        s += v; q += v * v;
    }
    if (t < F) { ls[t] = 0.f; lq[t] = 0.f; }
    __syncthreads();
    atomicAdd(&ls[c], s);
    atomicAdd(&lq[c], q);
    __syncthreads();
    if (t < F) { atomicAdd(&sums[t], ls[t]); atomicAdd(&ssq[t], lq[t]); }
}

template <int F>
__global__ void bn_finalize(const float* __restrict__ sums, const float* __restrict__ ssq,
                            const float* __restrict__ g, const float* __restrict__ be,
                            float* __restrict__ aArr, float* __restrict__ bArr) {
    int c = threadIdx.x;
    if (c < F) {
        float mu = sums[c] / (float)NN;
        float var = ssq[c] / (float)NN - mu * mu;
        float a = g[c] * rsqrtf(var + BNEPS);
        aArr[c] = a;
        bArr[c] = be[c] - mu * a;
    }
}

// ---------------- GAT factorized: precompute P_src/P_dst (16x8) and M (128x3), bgW ----------------
// xg = z @ Wg (z = relu(bn(h3)), 16-dim) is NEVER materialized.
// a_src[n][h] = z[n] . Psrc[:,h];  hg -> out folded into M[h][k][j] = (1/8) sum_c Wg[k][h*16+c] Wf[c][j]

__global__ void gat_mats(const float* __restrict__ Wg, const float* __restrict__ att_src,
                         const float* __restrict__ att_dst, const float* __restrict__ Wf,
                         const float* __restrict__ bg, float* __restrict__ Psrc,
                         float* __restrict__ Pdst, float* __restrict__ M,
                         float* __restrict__ bgW) {
    int t = threadIdx.x;  // 1024 threads, one block
    if (t < 128) {
        int k = t >> 3, h = t & 7;
        float s = 0.f, d = 0.f;
        for (int c = 0; c < 16; ++c) {
            float wv = Wg[k * 128 + h * 16 + c];
            s += wv * att_src[h * 16 + c];
            d += wv * att_dst[h * 16 + c];
        }
        Psrc[k * 8 + h] = s;
        Pdst[k * 8 + h] = d;
    } else if (t < 512) {
        int m = t - 128;
        if (m < 384) {
            int hk = m / 3, j = m - hk * 3;
            int H = hk >> 4, k = hk & 15;
            float s = 0.f;
            for (int c = 0; c < 16; ++c) s += Wg[k * 128 + H * 16 + c] * Wf[c * 3 + j];
            M[hk * 3 + j] = 0.125f * s;
        }
    } else if (t < 515) {
        int j = t - 512;
        float s = 0.f;
        for (int c = 0; c < 16; ++c) s += bg[c] * Wf[c * 3 + j];
        bgW[j] = s;
    }
}

// ---------------- gat_pre2: z (fp16 [NN][16]) + asrc/adst (fp32 [NN][8]) ----------------

__global__ void gat_pre2(const float* __restrict__ h3, const float* __restrict__ aArr,
                         const float* __restrict__ bArr, const float* __restrict__ Psrc,
                         const float* __restrict__ Pdst, __half* __restrict__ z,
                         float* __restrict__ asrc, float* __restrict__ adst) {
    __shared__ float Ps[128], Pd[128], aa[16], bb[16];
    int t = threadIdx.x;
    if (t < 128) { Ps[t] = Psrc[t]; Pd[t] = Pdst[t]; }
    if (t < 16) { aa[t] = aArr[t]; bb[t] = bArr[t]; }
    __syncthreads();
    int n = blockIdx.x * blockDim.x + t;
    if (n >= NN) return;
    float zv[16];
#pragma unroll
    for (int k = 0; k < 16; ++k) {
        float v = h3[(size_t)n * 16 + k];
        v = aa[k] * v + bb[k];
        zv[k] = v > 0.f ? v : 0.f;
    }
    __half2 zh[8];
#pragma unroll
    for (int k = 0; k < 8; ++k) zh[k] = __floats2half2_rn(zv[2 * k], zv[2 * k + 1]);
    float4* zo = (float4*)(z + (size_t)n * 16);
    zo[0] = ((float4*)zh)[0];
    zo[1] = ((float4*)zh)[1];
    float as[8], ad[8];
#pragma unroll
    for (int h = 0; h < 8; ++h) { as[h] = 0.f; ad[h] = 0.f; }
#pragma unroll
    for (int k = 0; k < 16; ++k) {
        float zk = zv[k];
#pragma unroll
        for (int h = 0; h < 8; ++h) {
            as[h] += zk * Ps[k * 8 + h];
            ad[h] += zk * Pd[k * 8 + h];
        }
    }
    float4* a4 = (float4*)(asrc + (size_t)n * 8);
    a4[0] = make_float4(as[0], as[1], as[2], as[3]);
    a4[1] = make_float4(as[4], as[5], as[6], as[7]);
    float4* d4 = (float4*)(adst + (size_t)n * 8);
    d4[0] = make_float4(ad[0], ad[1], ad[2], ad[3]);
    d4[1] = make_float4(ad[4], ad[5], ad[6], ad[7]);
}

// ---------------- gat_agg5: per-dst per-head weighted z-sums, normalized, fp16 out ----------------
// lane = sub(3b) | hh(1b) | q(2b): 8 edge slots, head-half, k-quad. acc[4h][4k].
// Sn[i][H*16+k] = ( sum_j w_Hj z_j[k] ) / W_H   (self-loop included)

__device__ __forceinline__ float leaky02(float x) { return x > 0.f ? x : 0.2f * x; }

__global__ void gat_agg5(const float2* __restrict__ z2, const float* __restrict__ asrc,
                         const float* __restrict__ adst, const int* __restrict__ rowptr,
                         const int* __restrict__ colA, __half* __restrict__ Sn) {
    const int lane = threadIdx.x & 63;
    const int q = lane & 3;
    const int hh = (lane >> 2) & 1;
    const int sub = lane >> 3;
    const int wid = (blockIdx.x * blockDim.x + threadIdx.x) >> 6;
    const int totalWaves = (gridDim.x * blockDim.x) >> 6;
    const float4* asrc4 = (const float4*)asrc;
    const float4* adst4 = (const float4*)adst;
    for (int i = wid; i < NN; i += totalWaves) {
        const int r0 = rowptr[i], r1 = rowptr[i + 1];
        const float4 adh = adst4[(size_t)i * 2 + hh];
        float acc[4][4];
        float wsum[4];
        {   // self loop (sub 0 only; others zero-init)
            float4 a = asrc4[(size_t)i * 2 + hh];
            float2 zr = z2[(size_t)i * 4 + q];
            const __half2* zp = (const __half2*)&zr;
            float2 f0 = __half22float2(zp[0]), f1 = __half22float2(zp[1]);
            float zf[4] = {f0.x, f0.y, f1.x, f1.y};
            float wq[4];
            wq[0] = (sub == 0) ? __expf(leaky02(a.x + adh.x)) : 0.f;
            wq[1] = (sub == 0) ? __expf(leaky02(a.y + adh.y)) : 0.f;
            wq[2] = (sub == 0) ? __expf(leaky02(a.z + adh.z)) : 0.f;
            wq[3] = (sub == 0) ? __expf(leaky02(a.w + adh.w)) : 0.f;
#pragma unroll
            for (int h = 0; h < 4; ++h) {
                wsum[h] = wq[h];
#pragma unroll
                for (int k = 0; k < 4; ++k) acc[h][k] = wq[h] * zf[k];
            }
        }
        for (int e = r0; e < r1; e += 8) {
            const int ee = e + sub;
            const bool val = ee < r1;
            const int j = val ? colA[ee] : i;
            float4 a = asrc4[(size_t)j * 2 + hh];
            float2 zr = z2[(size_t)j * 4 + q];
            const __half2* zp = (const __half2*)&zr;
            float2 f0 = __half22float2(zp[0]), f1 = __half22float2(zp[1]);
            float zf[4] = {f0.x, f0.y, f1.x, f1.y};
            float wq[4];
            wq[0] = val ? __expf(leaky02(a.x + adh.x)) : 0.f;
            wq[1] = val ? __expf(leaky02(a.y + adh.y)) : 0.f;
            wq[2] = val ? __expf(leaky02(a.z + adh.z)) : 0.f;
            wq[3] = val ? __expf(leaky02(a.w + adh.w)) : 0.f;
#pragma unroll
            for (int h = 0; h < 4; ++h) {
                wsum[h] += wq[h];
#pragma unroll
                for (int k = 0; k < 4; ++k) acc[h][k] += wq[h] * zf[k];
            }
        }
        // reduce over 8 edge slots (sub bits 3..5)
#pragma unroll
        for (int off = 8; off < 64; off <<= 1) {
#pragma unroll
            for (int h = 0; h < 4; ++h) {
                wsum[h] += __shfl_xor(wsum[h], off);
#pragma unroll
                for (int k = 0; k < 4; ++k) acc[h][k] += __shfl_xor(acc[h][k], off);
            }
        }
        if (lane < 8) {  // one lane per (hh,q): writes 4 heads x 4 k
#pragma unroll
            for (int h = 0; h < 4; ++h) {
                const float inv = 1.f / wsum[h];
                __half2 o[2];
                o[0] = __floats2half2_rn(acc[h][0] * inv, acc[h][1] * inv);
                o[1] = __floats2half2_rn(acc[h][2] * inv, acc[h][3] * inv);
                *(float2*)(Sn + (size_t)i * 128 + (hh * 4 + h) * 16 + q * 4) = *(float2*)o;
            }
        }
    }
}

// ---------------- graph bounds from sorted batch ----------------

__global__ void graph_bounds(const int* __restrict__ batch, int* __restrict__ gstart) {
    int n = blockIdx.x * blockDim.x + threadIdx.x;
    if (n < NN) {
        int bn = batch[n];
        int bp = (n == 0) ? -1 : batch[n - 1];
        for (int g = bp + 1; g <= bn; ++g) gstart[g] = n;
        if (n == NN - 1)
            for (int g = bn + 1; g <= GG; ++g) gstart[g] = NN;
    }
}

// ---------------- pool + classify (fused, atomic-free): one wave per graph ----------------
// out[g][j] = sum_{n in g} sum_{hk} Sn[n][hk] M[hk][j] + cnt_g*bgW[j] + bf[j]

__global__ void pool_final(const __half2* __restrict__ Sn2, const int* __restrict__ gstart,
                           const float* __restrict__ M, const float* __restrict__ bgW,
                           const float* __restrict__ bf, float* __restrict__ out) {
    const int lane = threadIdx.x & 63;
    const int g = (blockIdx.x * blockDim.x + threadIdx.x) >> 6;
    if (g >= GG) return;
    const int n0 = gstart[g], n1 = gstart[g + 1];
    float2 s = {0.f, 0.f};
    for (int n = n0; n < n1; ++n) {
        float2 v = __half22float2(Sn2[(size_t)n * 64 + lane]);
        s.x += v.x;
        s.y += v.y;
    }
    float o[3];
#pragma unroll
    for (int j = 0; j < 3; ++j)
        o[j] = s.x * M[(2 * lane) * 3 + j] + s.y * M[(2 * lane + 1) * 3 + j];
#pragma unroll
    for (int off = 1; off < 64; off <<= 1) {
#pragma unroll
        for (int j = 0; j < 3; ++j) o[j] += __shfl_xor(o[j], off);
    }
    if (lane == 0) {
        float cnt = (float)(n1 - n0);
#pragma unroll
        for (int j = 0; j < 3; ++j) out[g * 3 + j] = o[j] + cnt * bgW[j] + bf[j];
    }
}

// ---------------- launcher ----------------

extern "C" void kernel_launch(void* const* d_in, const int* in_sizes, int n_in,
                              void* d_out, int out_size, void* d_ws, size_t ws_size,
                              hipStream_t stream) {
    const float* x = (const float*)d_in[0];
    const int* ei = (const int*)d_in[1];
    const int* batch = (const int*)d_in[2];
    const float* W1 = (const float*)d_in[3];  const float* b1 = (const float*)d_in[4];
    const float* g1 = (const float*)d_in[5];  const float* be1 = (const float*)d_in[6];
    const float* W2 = (const float*)d_in[7];  const float* b2 = (const float*)d_in[8];
    const float* g2 = (const float*)d_in[9];  const float* be2 = (const float*)d_in[10];
    const float* W3 = (const float*)d_in[11]; const float* b3 = (const float*)d_in[12];
    const float* g3 = (const float*)d_in[13]; const float* be3 = (const float*)d_in[14];
    const float* Wg = (const float*)d_in[15];
    const float* att_src = (const float*)d_in[16];
    const float* att_dst = (const float*)d_in[17];
    const float* bg = (const float*)d_in[18];
    const float* Wf = (const float*)d_in[19];
    const float* bf = (const float*)d_in[20];
    float* out = (float*)d_out;

    char* w = (char*)d_ws;
    auto alloc = [&](size_t bytes) -> char* {
        char* p = w;
        w += (bytes + 255) & ~(size_t)255;
        return p;
    };
    // --- zeroed region (one memset) ---
    int* fill = (int*)alloc((size_t)NN * 4);
    float* sums1 = (float*)alloc(64 * 4); float* ssq1 = (float*)alloc(64 * 4);
    float* sums2 = (float*)alloc(32 * 4); float* ssq2 = (float*)alloc(32 * 4);
    float* sums3 = (float*)alloc(16 * 4); float* ssq3 = (float*)alloc(16 * 4);
    size_t zeroBytes = (size_t)(w - (char*)d_ws);
    // --- rest ---
    float* a1 = (float*)alloc(64 * 4); float* bh1 = (float*)alloc(64 * 4);
    float* a2 = (float*)alloc(32 * 4); float* bh2 = (float*)alloc(32 * 4);
    float* a3 = (float*)alloc(16 * 4); float* bh3 = (float*)alloc(16 * 4);
    float* Psrc = (float*)alloc(128 * 4);
    float* Pdst = (float*)alloc(128 * 4);
    float* Mm = (float*)alloc(384 * 4);
    float* bgW = (float*)alloc(3 * 4);
    int* gstart = (int*)alloc((size_t)(GG + 1) * 4);
    int* bsum = (int*)alloc(128 * 4);
    int* boff = (int*)alloc(128 * 4);
    int* rowptr = (int*)alloc((size_t)(NN + 1) * 4);
    int* colA = (int*)alloc((size_t)EE * 4);
    float* dinv = (float*)alloc((size_t)NN * 4);
    char* A = alloc((size_t)NN * 64 * 4);  // 25.6 MB scratch block A
    char* B = alloc((size_t)NN * 64 * 4);  // 25.6 MB scratch block B

    // lifetime-based aliases
    __half* xsc  = (__half*)B;                               // [NN,20] fp16   4.0 MB
    float*  aggx = (float*)(B + (size_t)NN * 32 * 2);        // [NN,20] fp32   8.0 MB
    float*  h1   = (float*)A;                                // [NN,64] fp32  25.6 MB
    __half* hs2  = (__half*)B;                               // [NN,32] fp16   6.4 MB
    float*  h2   = (float*)(B + (size_t)NN * 32 * 2);        // [NN,32] fp32  12.8 MB
    __half* hs3  = (__half*)A;                               // [NN,16] fp16   3.2 MB
    float*  h3   = (float*)(A + (size_t)NN * 16 * 2);        // [NN,16] fp32   6.4 MB
    __half* z    = (__half*)(A + (size_t)NN * 24 * 4);       // [NN,16] fp16   3.2 MB
    float*  asrc = (float*)(A + (size_t)NN * 32 * 4);        // [NN,8]  fp32   3.2 MB
    float*  adst = (float*)(A + (size_t)NN * 40 * 4);        // [NN,8]  fp32   3.2 MB
    __half* Sn   = (__half*)B;                               // [NN,128] fp16 25.6 MB

    hipMemsetAsync(d_ws, 0, zeroBytes, stream);

    count_x<<<2048, 256, 0, stream>>>(ei, fill);
    scanA<<<NSCANBLK, SCAN_BLK, 0, stream>>>(fill, bsum);
    scanB<<<1, SCAN_BLK, 0, stream>>>(bsum, boff);
    scanC<<<NSCANBLK, SCAN_BLK, 0, stream>>>(fill, boff, rowptr, dinv);
    scatter_x<<<2048, 256, 0, stream>>>(ei, fill, colA);
    gat_mats<<<1, 1024, 0, stream>>>(Wg, att_src, att_dst, Wf, bg, Psrc, Pdst, Mm, bgW);
    graph_bounds<<<(NN + 255) / 256, 256, 0, stream>>>(batch, gstart);

    // layer 1: aggregate x first (20ch tight fp16), then GEMM 20->64 (+b1)
    scale_x<<<(NN * 20 + 255) / 256, 256, 0, stream>>>(x, dinv, xsc);
    agg_half<10, 20><<<2048, 256, 0, stream>>>((const __half2*)xsc, rowptr, colA, dinv, nullptr, aggx);
    gemm_k<20, 64, false, false><<<2048, 256, 0, stream>>>(aggx, nullptr, nullptr, W1, dinv, b1, h1, nullptr);
    bn_stats<64><<<512, 256, 0, stream>>>(h1, sums1, ssq1);
    bn_finalize<64><<<1, 64, 0, stream>>>(sums1, ssq1, g1, be1, a1, bh1);

    // layer 2: 64 -> 32 (fp16 pre-agg buffer)
    gemm_k<64, 32, true, true><<<2048, 256, 0, stream>>>(h1, a1, bh1, W2, dinv, nullptr, nullptr, hs2);
    agg_half<16, 32><<<2048, 256, 0, stream>>>((const __half2*)hs2, rowptr, colA, dinv, b2, h2);
    bn_stats<32><<<512, 256, 0, stream>>>(h2, sums2, ssq2);
    bn_finalize<32><<<1, 64, 0, stream>>>(sums2, ssq2, g2, be2, a2, bh2);

    // layer 3: 32 -> 16 (fp16 pre-agg buffer)
    gemm_k<32, 16, true, true><<<2048, 256, 0, stream>>>(h2, a2, bh2, W3, dinv, nullptr, nullptr, hs3);
    agg_half<8, 16><<<2048, 256, 0, stream>>>((const __half2*)hs3, rowptr, colA, dinv, b3, h3);
    bn_stats<16><<<512, 256, 0, stream>>>(h3, sums3, ssq3);
    bn_finalize<16><<<1, 64, 0, stream>>>(sums3, ssq3, g3, be3, a3, bh3);

    // GAT factorized: z/asrc/adst (L2-resident gathers), per-head sums, fused pool+classify
    gat_pre2<<<(NN + 255) / 256, 256, 0, stream>>>(h3, a3, bh3, Psrc, Pdst, z, asrc, adst);
    gat_agg5<<<2048, 256, 0, stream>>>((const float2*)z, asrc, adst, rowptr, colA, Sn);
    pool_final<<<(GG * 64 + 255) / 256, 256, 0, stream>>>((const __half2*)Sn, gstart, Mm, bgW, bf, out);
}